// Round 7
// baseline (322.921 us; speedup 1.0000x reference)
//
#include <hip/hip_runtime.h>

#define N_NODES 100000
#define N_EDGES 1600000
#define DIN 64
#define DOUT 32
#define NEG_SLOPE 0.01f
#define NBLK ((N_NODES + 255) / 256)  // 391
#define RANGE (N_NODES / 8)           // 12500 nodes per XCD range
#define GROUP_BLOCKS 512              // blocks per range-group
#define NCHUNK ((N_EDGES + 255) / 256)  // 6250

__device__ inline unsigned short f2bf(float f) {  // RNE
    unsigned int u = __float_as_uint(f);
    unsigned int r = (u + 0x7fffu + ((u >> 16) & 1u)) >> 16;
    return (unsigned short)r;
}
__device__ inline float bflo(unsigned int p) { return __uint_as_float(p << 16); }
__device__ inline float bfhi(unsigned int p) { return __uint_as_float(p & 0xffff0000u); }
#define NTL(p) __builtin_nontemporal_load(p)

// ---------------- CSR build ----------------
__global__ void zero_cnt_kernel(int* __restrict__ cnt) {
    int i = blockIdx.x * blockDim.x + threadIdx.x;
    if (i < N_NODES) cnt[i] = 0;
}

// degree histogram, XCD-range partitioned (group g = blockIdx&7 ~ XCD).
// dst read is non-temporal so the stream doesn't evict the L2-resident cnt slice.
__global__ void count8_kernel(const int* __restrict__ dst, int* __restrict__ cnt) {
    int g = blockIdx.x & 7;
    int b = blockIdx.x >> 3;
    int lo = g * RANGE;
    for (int c = b; c < NCHUNK; c += GROUP_BLOCKS) {
        int e = c * 256 + threadIdx.x;
        int d = NTL(&dst[e]);
        if ((unsigned)(d - lo) < (unsigned)RANGE) atomicAdd(&cnt[d], 1);
    }
}

__global__ void blocksum_kernel(const int* __restrict__ cnt, int* __restrict__ bsum) {
    int i = blockIdx.x * 256 + threadIdx.x;
    int v = (i < N_NODES) ? cnt[i] : 0;
#pragma unroll
    for (int off = 32; off; off >>= 1) v += __shfl_down(v, off);
    __shared__ int ws[4];
    if ((threadIdx.x & 63) == 0) ws[threadIdx.x >> 6] = v;
    __syncthreads();
    if (threadIdx.x == 0) bsum[blockIdx.x] = ws[0] + ws[1] + ws[2] + ws[3];
}

__global__ __launch_bounds__(512) void scan_bsum_kernel(const int* __restrict__ bsum,
                                                        int* __restrict__ bofs) {
    __shared__ int sh[512];
    int t = threadIdx.x;
    int v = (t < NBLK) ? bsum[t] : 0;
    sh[t] = v;
    __syncthreads();
    for (int off = 1; off < 512; off <<= 1) {
        int a = sh[t];
        int add = (t >= off) ? sh[t - off] : 0;
        __syncthreads();
        sh[t] = a + add;
        __syncthreads();
    }
    if (t < NBLK) bofs[t] = sh[t] - v;  // exclusive
}

__global__ void rowptr_kernel(const int* __restrict__ cnt, const int* __restrict__ bofs,
                              int* __restrict__ rowptr, int* __restrict__ pos,
                              float* __restrict__ dinv) {
    int i = blockIdx.x * 256 + threadIdx.x;
    int v = (i < N_NODES) ? cnt[i] : 0;
    int lane = threadIdx.x & 63;
    int w = threadIdx.x >> 6;
    int x = v;
#pragma unroll
    for (int off = 1; off < 64; off <<= 1) {
        int n = __shfl_up(x, off);
        if (lane >= off) x += n;
    }
    __shared__ int wtot[4];
    if (lane == 63) wtot[w] = x;
    __syncthreads();
    int wofs = 0;
    for (int k = 0; k < w; ++k) wofs += wtot[k];
    int excl = x - v + wofs + bofs[blockIdx.x];
    if (i < N_NODES) {
        rowptr[i] = excl;
        pos[i] = excl;
        dinv[i] = rsqrtf((float)(v + 1));
        if (i == N_NODES - 1) rowptr[N_NODES] = excl + v;
    }
}

// CSR fill, XCD-range partitioned; nt reads keep dirty colsrc/pos lines in L2
// until fully combined.
__global__ void fill8_kernel(const int* __restrict__ src, const int* __restrict__ dst,
                             int* __restrict__ pos, int* __restrict__ colsrc) {
    int g = blockIdx.x & 7;
    int b = blockIdx.x >> 3;
    int lo = g * RANGE;
    for (int c = b; c < NCHUNK; c += GROUP_BLOCKS) {
        int e = c * 256 + threadIdx.x;
        int d = NTL(&dst[e]);
        if ((unsigned)(d - lo) < (unsigned)RANGE) {
            int idx = atomicAdd(&pos[d], 1);
            colsrc[idx] = NTL(&src[e]);
        }
    }
}

// ---------------- GEMM: Hn = (X @ W) * dinv[row], bf16 out ----------------
__global__ void gemm_k64_n64_kernel(const float* __restrict__ X, const float* __restrict__ W,
                                    const float* __restrict__ dinv,
                                    unsigned short* __restrict__ Hn) {
    __shared__ float Ws[64 * 64];
    __shared__ float Xs[4][64];
    int tid = threadIdx.x;
    {
        const float4* Wv = (const float4*)W;
        float4* Wsv = (float4*)Ws;
#pragma unroll
        for (int i = 0; i < 4; ++i) Wsv[tid + 256 * i] = Wv[tid + 256 * i];
    }
    int row0 = blockIdx.x * 4;
    int r = tid >> 6;
    int col = tid & 63;
    Xs[r][col] = X[(row0 + r) * 64 + col];
    __syncthreads();

    float sum = 0.f;
#pragma unroll
    for (int k = 0; k < 64; ++k) sum += Xs[r][k] * Ws[k * 64 + col];
    Hn[(row0 + r) * 64 + col] = f2bf(sum * dinv[row0 + r]);
}

__global__ void gemm_k64_n32_kernel(const float* __restrict__ X, const float* __restrict__ W,
                                    const float* __restrict__ dinv,
                                    unsigned short* __restrict__ Hn) {
    __shared__ float Ws[64 * 32];
    __shared__ float Xs[8][64];
    int tid = threadIdx.x;
    {
        const float4* Wv = (const float4*)W;
        float4* Wsv = (float4*)Ws;
#pragma unroll
        for (int i = 0; i < 2; ++i) Wsv[tid + 256 * i] = Wv[tid + 256 * i];
    }
    int row0 = blockIdx.x * 8;
    {
        int idx = tid;
#pragma unroll
        for (int i = 0; i < 2; ++i, idx += 256) Xs[idx >> 6][idx & 63] = X[row0 * 64 + idx];
    }
    __syncthreads();

    int r = tid >> 5;
    int col = tid & 31;
    float sum = 0.f;
#pragma unroll
    for (int k = 0; k < 64; ++k) sum += Xs[r][k] * Ws[k * 32 + col];
    Hn[(row0 + r) * 32 + col] = f2bf(sum * dinv[row0 + r]);
}

// ---------------- gather aggregation (bf16 rows, norm pre-folded) ----------------
__global__ void gather64_kernel(const unsigned short* __restrict__ Hn,
                                const int* __restrict__ rowptr, const int* __restrict__ colsrc,
                                const float* __restrict__ dinv, const float* __restrict__ bias,
                                float* __restrict__ out) {
    int wid = (blockIdx.x * blockDim.x + threadIdx.x) >> 6;
    int lane = threadIdx.x & 63;
    if (wid >= N_NODES) return;
    int v = wid;
    int half = lane >> 5;
    int sl = lane & 31;
    int hb = half << 5;
    int beg = rowptr[v], end = rowptr[v + 1];
    int len = end - beg;
    int mid = beg + ((len + 1) >> 1);
    int l0 = half ? mid : beg;
    int l1 = half ? end : mid;

    float acc0 = 0.f, acc1 = 0.f, b0 = 0.f, b1 = 0.f;
    if (half == 0) {  // self row once
        unsigned int rw = ((const unsigned int*)(Hn + (size_t)v * 64))[sl];
        acc0 = bflo(rw);
        acc1 = bfhi(rw);
    }
    for (int j0 = l0; j0 < l1; j0 += 32) {
        int myj = j0 + sl;
        int s = (myj < l1) ? NTL(&colsrc[myj]) : 0;
        int cnt = min(32, l1 - j0);
        int t = 0;
        for (; t + 2 <= cnt; t += 2) {
            int s0 = __shfl(s, hb + t);
            int s1 = __shfl(s, hb + t + 1);
            unsigned int r0 = ((const unsigned int*)(Hn + (size_t)s0 * 64))[sl];
            unsigned int r1 = ((const unsigned int*)(Hn + (size_t)s1 * 64))[sl];
            acc0 += bflo(r0);
            acc1 += bfhi(r0);
            b0 += bflo(r1);
            b1 += bfhi(r1);
        }
        if (t < cnt) {
            int s0 = __shfl(s, hb + t);
            unsigned int r0 = ((const unsigned int*)(Hn + (size_t)s0 * 64))[sl];
            acc0 += bflo(r0);
            acc1 += bfhi(r0);
        }
    }
    acc0 += b0;
    acc1 += b1;
    acc0 += __shfl_xor(acc0, 32);
    acc1 += __shfl_xor(acc1, 32);
    if (half == 0) {
        float dv = dinv[v];
        float2 bb = ((const float2*)bias)[sl];
        float o0 = acc0 * dv + bb.x;
        float o1 = acc1 * dv + bb.y;
        o0 = o0 > 0.f ? o0 : NEG_SLOPE * o0;
        o1 = o1 > 0.f ? o1 : NEG_SLOPE * o1;
        ((float2*)(out + (size_t)v * 64))[sl] = make_float2(o0, o1);
    }
}

__global__ void gather32_kernel(const unsigned short* __restrict__ Hn,
                                const int* __restrict__ rowptr, const int* __restrict__ colsrc,
                                const float* __restrict__ dinv, const float* __restrict__ bias,
                                float* __restrict__ out) {
    int wid = (blockIdx.x * blockDim.x + threadIdx.x) >> 6;
    int lane = threadIdx.x & 63;
    if (wid >= N_NODES) return;
    int v = wid;
    int q = lane >> 4;
    int sl = lane & 15;
    int qb = q << 4;
    int beg = rowptr[v], end = rowptr[v + 1];
    int len = end - beg;
    int qs = (len + 3) >> 2;
    int l0 = beg + min(len, qs * q);
    int l1 = beg + min(len, qs * (q + 1));

    float acc0 = 0.f, acc1 = 0.f, b0 = 0.f, b1 = 0.f;
    if (q == 0) {  // self row once
        unsigned int rw = ((const unsigned int*)(Hn + (size_t)v * 32))[sl];
        acc0 = bflo(rw);
        acc1 = bfhi(rw);
    }
    for (int j0 = l0; j0 < l1; j0 += 16) {
        int myj = j0 + sl;
        int s = (myj < l1) ? NTL(&colsrc[myj]) : 0;
        int cnt = min(16, l1 - j0);
        int t = 0;
        for (; t + 2 <= cnt; t += 2) {
            int s0 = __shfl(s, qb + t);
            int s1 = __shfl(s, qb + t + 1);
            unsigned int r0 = ((const unsigned int*)(Hn + (size_t)s0 * 32))[sl];
            unsigned int r1 = ((const unsigned int*)(Hn + (size_t)s1 * 32))[sl];
            acc0 += bflo(r0);
            acc1 += bfhi(r0);
            b0 += bflo(r1);
            b1 += bfhi(r1);
        }
        if (t < cnt) {
            int s0 = __shfl(s, qb + t);
            unsigned int r0 = ((const unsigned int*)(Hn + (size_t)s0 * 32))[sl];
            acc0 += bflo(r0);
            acc1 += bfhi(r0);
        }
    }
    acc0 += b0;
    acc1 += b1;
    acc0 += __shfl_xor(acc0, 16);
    acc1 += __shfl_xor(acc1, 16);
    acc0 += __shfl_xor(acc0, 32);
    acc1 += __shfl_xor(acc1, 32);
    if (q == 0) {
        float dv = dinv[v];
        float2 bb = ((const float2*)bias)[sl];
        float o0 = acc0 * dv + bb.x;
        float o1 = acc1 * dv + bb.y;
        ((float2*)(out + (size_t)v * 32))[sl] = make_float2(o0, o1);
    }
}

extern "C" void kernel_launch(void* const* d_in, const int* in_sizes, int n_in,
                              void* d_out, int out_size, void* d_ws, size_t ws_size,
                              hipStream_t stream) {
    const float* x = (const float*)d_in[0];
    const int* ei = (const int*)d_in[1];  // [2,E]: src row then dst row
    const float* W1 = (const float*)d_in[2];
    const float* b1 = (const float*)d_in[3];
    const float* W2 = (const float*)d_in[4];
    const float* b2 = (const float*)d_in[5];
    float* out = (float*)d_out;

    const int* src = ei;
    const int* dst = ei + N_EDGES;

    // workspace layout (~47 MB)
    float* dinv = (float*)d_ws;                       // N
    int* rowptr = (int*)(dinv + N_NODES);             // N+1
    int* cnt = rowptr + N_NODES + 1;                  // N
    int* pos = cnt + N_NODES;                         // N
    int* bsum = pos + N_NODES;                        // NBLK
    int* bofs = bsum + NBLK;                          // NBLK
    int* colsrc = bofs + NBLK;                        // E
    unsigned short* h1n = (unsigned short*)(colsrc + N_EDGES);  // N*64 bf16
    float* h1p = (float*)(h1n + (size_t)N_NODES * DIN);         // N*64 f32
    unsigned short* h2n = h1n;  // alias: h1n dead after gather64

    // CSR build + norms
    zero_cnt_kernel<<<NBLK, 256, 0, stream>>>(cnt);
    count8_kernel<<<8 * GROUP_BLOCKS, 256, 0, stream>>>(dst, cnt);
    blocksum_kernel<<<NBLK, 256, 0, stream>>>(cnt, bsum);
    scan_bsum_kernel<<<1, 512, 0, stream>>>(bsum, bofs);
    rowptr_kernel<<<NBLK, 256, 0, stream>>>(cnt, bofs, rowptr, pos, dinv);
    fill8_kernel<<<8 * GROUP_BLOCKS, 256, 0, stream>>>(src, dst, pos, colsrc);

    // layer 1
    gemm_k64_n64_kernel<<<N_NODES / 4, 256, 0, stream>>>(x, W1, dinv, h1n);
    gather64_kernel<<<(N_NODES * 64 + 255) / 256, 256, 0, stream>>>(h1n, rowptr, colsrc, dinv, b1, h1p);

    // layer 2
    gemm_k64_n32_kernel<<<N_NODES / 8, 256, 0, stream>>>(h1p, W2, dinv, h2n);
    gather32_kernel<<<(N_NODES * 64 + 255) / 256, 256, 0, stream>>>(h2n, rowptr, colsrc, dinv, b2, out);
}

// Round 8
// 224.864 us; speedup vs baseline: 1.4361x; 1.4361x over previous
//
#include <hip/hip_runtime.h>

#define N_NODES 100000
#define N_EDGES 1600000
#define DIN 64
#define DOUT 32
#define NEG_SLOPE 0.01f
#define NBUCK 196          // buckets of 512 nodes (dst >> 9)
#define CAP 12288          // staging capacity per bucket (mean 8163, ~36 sigma)
#define CH 4096            // edges per binpass1 block
#define NB1 ((N_EDGES + CH - 1) / CH)  // 391

__device__ inline unsigned short f2bf(float f) {  // RNE
    unsigned int u = __float_as_uint(f);
    unsigned int r = (u + 0x7fffu + ((u >> 16) & 1u)) >> 16;
    return (unsigned short)r;
}
__device__ inline float bflo(unsigned int p) { return __uint_as_float(p << 16); }
__device__ inline float bfhi(unsigned int p) { return __uint_as_float(p & 0xffff0000u); }
#define NTL(p) __builtin_nontemporal_load(p)

// ---------------- binning CSR build ----------------
__global__ void zero_bf_kernel(int* __restrict__ bucketfill) {
    if (threadIdx.x < NBUCK) bucketfill[threadIdx.x] = 0;
}

// block-local binning: LDS hist over 196 buckets, one global reservation per
// (block,bucket), scatter packed payloads into run-contiguous staging.
__global__ __launch_bounds__(256) void binpass1_kernel(const int* __restrict__ src,
                                                       const int* __restrict__ dst,
                                                       int* __restrict__ bucketfill,
                                                       unsigned int* __restrict__ staging) {
    __shared__ int hist[NBUCK];
    __shared__ int cur[NBUCK];  // global append cursor per bucket for this block
    int tid = threadIdx.x;
    for (int t = tid; t < NBUCK; t += 256) hist[t] = 0;
    __syncthreads();

    int e0 = blockIdx.x * CH + tid;
    int bk[16];
    unsigned int pay[16];
#pragma unroll
    for (int i = 0; i < 16; ++i) {
        int e = e0 + i * 256;
        if (e < N_EDGES) {
            int d = NTL(&dst[e]);
            int s = NTL(&src[e]);
            bk[i] = d >> 9;
            pay[i] = (unsigned int)s | ((unsigned int)(d & 511) << 17);
            atomicAdd(&hist[bk[i]], 1);
        } else {
            bk[i] = -1;
        }
    }
    __syncthreads();
    for (int t = tid; t < NBUCK; t += 256) {
        int h = hist[t];
        cur[t] = h ? atomicAdd(&bucketfill[t], h) : 0;
    }
    __syncthreads();
#pragma unroll
    for (int i = 0; i < 16; ++i) {
        if (bk[i] >= 0) {
            int idx = atomicAdd(&cur[bk[i]], 1);
            if (idx < CAP) staging[(size_t)bk[i] * CAP + idx] = pay[i];
        }
    }
}

// exclusive scan of 196 bucket totals; also rowptr[N] = E
__global__ __launch_bounds__(256) void scan_buckets_kernel(const int* __restrict__ bucketfill,
                                                           int* __restrict__ bucketbase,
                                                           int* __restrict__ rowptr) {
    __shared__ int sh[256];
    int t = threadIdx.x;
    int v = (t < NBUCK) ? bucketfill[t] : 0;
    sh[t] = v;
    __syncthreads();
    for (int off = 1; off < 256; off <<= 1) {
        int a = sh[t];
        int add = (t >= off) ? sh[t - off] : 0;
        __syncthreads();
        sh[t] = a + add;
        __syncthreads();
    }
    if (t < NBUCK) bucketbase[t] = sh[t] - v;
    if (t == 0) rowptr[N_NODES] = N_EDGES;
}

// per-bucket: node histogram -> scan -> rowptr/dinv -> exact CSR placement.
// colsrc slice (~32KB) is dirty only while this block runs -> full-line write-backs.
__global__ __launch_bounds__(256) void binpass2_kernel(const unsigned int* __restrict__ staging,
                                                       const int* __restrict__ bucketfill,
                                                       const int* __restrict__ bucketbase,
                                                       int* __restrict__ rowptr,
                                                       float* __restrict__ dinv,
                                                       int* __restrict__ colsrc) {
    __shared__ int hist[512];
    __shared__ int posl[512];
    __shared__ int psum[256];
    int b = blockIdx.x;
    int tid = threadIdx.x;
    int base_node = b << 9;
    int nn = min(512, N_NODES - base_node);
    int len = min(bucketfill[b], CAP);
    int bbase = bucketbase[b];
    const unsigned int* stg = staging + (size_t)b * CAP;

    hist[tid] = 0;
    hist[tid + 256] = 0;
    __syncthreads();
    for (int i = tid; i < len; i += 256) atomicAdd(&hist[NTL(&stg[i]) >> 17], 1);
    __syncthreads();

    // exclusive scan of 512 via 256 pairs
    int a = hist[2 * tid], c = hist[2 * tid + 1];
    psum[tid] = a + c;
    __syncthreads();
    for (int off = 1; off < 256; off <<= 1) {
        int v = psum[tid];
        int add = (tid >= off) ? psum[tid - off] : 0;
        __syncthreads();
        psum[tid] = v + add;
        __syncthreads();
    }
    int pex = tid ? psum[tid - 1] : 0;
    // nodes 2*tid, 2*tid+1
    {
        int j0 = 2 * tid, j1 = 2 * tid + 1;
        int e0 = bbase + pex;
        int e1 = e0 + a;
        posl[j0] = e0;
        posl[j1] = e1;
        if (j0 < nn) {
            rowptr[base_node + j0] = e0;
            dinv[base_node + j0] = rsqrtf((float)(a + 1));
        }
        if (j1 < nn) {
            rowptr[base_node + j1] = e1;
            dinv[base_node + j1] = rsqrtf((float)(c + 1));
        }
    }
    __syncthreads();
    for (int i = tid; i < len; i += 256) {
        unsigned int pay = NTL(&stg[i]);
        int dlow = (int)(pay >> 17);
        int idx = atomicAdd(&posl[dlow], 1);
        colsrc[idx] = (int)(pay & 0x1FFFFu);
    }
}

// ---------------- GEMM: Hn = (X @ W) * dinv[row], bf16 out ----------------
__global__ void gemm_k64_n64_kernel(const float* __restrict__ X, const float* __restrict__ W,
                                    const float* __restrict__ dinv,
                                    unsigned short* __restrict__ Hn) {
    __shared__ float Ws[64 * 64];
    __shared__ float Xs[4][64];
    int tid = threadIdx.x;
    {
        const float4* Wv = (const float4*)W;
        float4* Wsv = (float4*)Ws;
#pragma unroll
        for (int i = 0; i < 4; ++i) Wsv[tid + 256 * i] = Wv[tid + 256 * i];
    }
    int row0 = blockIdx.x * 4;
    int r = tid >> 6;
    int col = tid & 63;
    Xs[r][col] = X[(row0 + r) * 64 + col];
    __syncthreads();

    float sum = 0.f;
#pragma unroll
    for (int k = 0; k < 64; ++k) sum += Xs[r][k] * Ws[k * 64 + col];
    Hn[(row0 + r) * 64 + col] = f2bf(sum * dinv[row0 + r]);
}

__global__ void gemm_k64_n32_kernel(const float* __restrict__ X, const float* __restrict__ W,
                                    const float* __restrict__ dinv,
                                    unsigned short* __restrict__ Hn) {
    __shared__ float Ws[64 * 32];
    __shared__ float Xs[8][64];
    int tid = threadIdx.x;
    {
        const float4* Wv = (const float4*)W;
        float4* Wsv = (float4*)Ws;
#pragma unroll
        for (int i = 0; i < 2; ++i) Wsv[tid + 256 * i] = Wv[tid + 256 * i];
    }
    int row0 = blockIdx.x * 8;
    {
        int idx = tid;
#pragma unroll
        for (int i = 0; i < 2; ++i, idx += 256) Xs[idx >> 6][idx & 63] = X[row0 * 64 + idx];
    }
    __syncthreads();

    int r = tid >> 5;
    int col = tid & 31;
    float sum = 0.f;
#pragma unroll
    for (int k = 0; k < 64; ++k) sum += Xs[r][k] * Ws[k * 32 + col];
    Hn[(row0 + r) * 32 + col] = f2bf(sum * dinv[row0 + r]);
}

// ---------------- gather aggregation (bf16 rows, norm pre-folded) ----------------
__global__ void gather64_kernel(const unsigned short* __restrict__ Hn,
                                const int* __restrict__ rowptr, const int* __restrict__ colsrc,
                                const float* __restrict__ dinv, const float* __restrict__ bias,
                                float* __restrict__ out) {
    int wid = (blockIdx.x * blockDim.x + threadIdx.x) >> 6;
    int lane = threadIdx.x & 63;
    if (wid >= N_NODES) return;
    int v = wid;
    int half = lane >> 5;
    int sl = lane & 31;
    int hb = half << 5;
    int beg = rowptr[v], end = rowptr[v + 1];
    int len = end - beg;
    int mid = beg + ((len + 1) >> 1);
    int l0 = half ? mid : beg;
    int l1 = half ? end : mid;

    float acc0 = 0.f, acc1 = 0.f, b0 = 0.f, b1 = 0.f;
    if (half == 0) {  // self row once
        unsigned int rw = ((const unsigned int*)(Hn + (size_t)v * 64))[sl];
        acc0 = bflo(rw);
        acc1 = bfhi(rw);
    }
    for (int j0 = l0; j0 < l1; j0 += 32) {
        int myj = j0 + sl;
        int s = (myj < l1) ? NTL(&colsrc[myj]) : 0;
        int cnt = min(32, l1 - j0);
        int t = 0;
        for (; t + 2 <= cnt; t += 2) {
            int s0 = __shfl(s, hb + t);
            int s1 = __shfl(s, hb + t + 1);
            unsigned int r0 = ((const unsigned int*)(Hn + (size_t)s0 * 64))[sl];
            unsigned int r1 = ((const unsigned int*)(Hn + (size_t)s1 * 64))[sl];
            acc0 += bflo(r0);
            acc1 += bfhi(r0);
            b0 += bflo(r1);
            b1 += bfhi(r1);
        }
        if (t < cnt) {
            int s0 = __shfl(s, hb + t);
            unsigned int r0 = ((const unsigned int*)(Hn + (size_t)s0 * 64))[sl];
            acc0 += bflo(r0);
            acc1 += bfhi(r0);
        }
    }
    acc0 += b0;
    acc1 += b1;
    acc0 += __shfl_xor(acc0, 32);
    acc1 += __shfl_xor(acc1, 32);
    if (half == 0) {
        float dv = dinv[v];
        float2 bb = ((const float2*)bias)[sl];
        float o0 = acc0 * dv + bb.x;
        float o1 = acc1 * dv + bb.y;
        o0 = o0 > 0.f ? o0 : NEG_SLOPE * o0;
        o1 = o1 > 0.f ? o1 : NEG_SLOPE * o1;
        ((float2*)(out + (size_t)v * 64))[sl] = make_float2(o0, o1);
    }
}

__global__ void gather32_kernel(const unsigned short* __restrict__ Hn,
                                const int* __restrict__ rowptr, const int* __restrict__ colsrc,
                                const float* __restrict__ dinv, const float* __restrict__ bias,
                                float* __restrict__ out) {
    int wid = (blockIdx.x * blockDim.x + threadIdx.x) >> 6;
    int lane = threadIdx.x & 63;
    if (wid >= N_NODES) return;
    int v = wid;
    int q = lane >> 4;
    int sl = lane & 15;
    int qb = q << 4;
    int beg = rowptr[v], end = rowptr[v + 1];
    int len = end - beg;
    int qs = (len + 3) >> 2;
    int l0 = beg + min(len, qs * q);
    int l1 = beg + min(len, qs * (q + 1));

    float acc0 = 0.f, acc1 = 0.f, b0 = 0.f, b1 = 0.f;
    if (q == 0) {  // self row once
        unsigned int rw = ((const unsigned int*)(Hn + (size_t)v * 32))[sl];
        acc0 = bflo(rw);
        acc1 = bfhi(rw);
    }
    for (int j0 = l0; j0 < l1; j0 += 16) {
        int myj = j0 + sl;
        int s = (myj < l1) ? NTL(&colsrc[myj]) : 0;
        int cnt = min(16, l1 - j0);
        int t = 0;
        for (; t + 2 <= cnt; t += 2) {
            int s0 = __shfl(s, qb + t);
            int s1 = __shfl(s, qb + t + 1);
            unsigned int r0 = ((const unsigned int*)(Hn + (size_t)s0 * 32))[sl];
            unsigned int r1 = ((const unsigned int*)(Hn + (size_t)s1 * 32))[sl];
            acc0 += bflo(r0);
            acc1 += bfhi(r0);
            b0 += bflo(r1);
            b1 += bfhi(r1);
        }
        if (t < cnt) {
            int s0 = __shfl(s, qb + t);
            unsigned int r0 = ((const unsigned int*)(Hn + (size_t)s0 * 32))[sl];
            acc0 += bflo(r0);
            acc1 += bfhi(r0);
        }
    }
    acc0 += b0;
    acc1 += b1;
    acc0 += __shfl_xor(acc0, 16);
    acc1 += __shfl_xor(acc1, 16);
    acc0 += __shfl_xor(acc0, 32);
    acc1 += __shfl_xor(acc1, 32);
    if (q == 0) {
        float dv = dinv[v];
        float2 bb = ((const float2*)bias)[sl];
        float o0 = acc0 * dv + bb.x;
        float o1 = acc1 * dv + bb.y;
        ((float2*)(out + (size_t)v * 32))[sl] = make_float2(o0, o1);
    }
}

extern "C" void kernel_launch(void* const* d_in, const int* in_sizes, int n_in,
                              void* d_out, int out_size, void* d_ws, size_t ws_size,
                              hipStream_t stream) {
    const float* x = (const float*)d_in[0];
    const int* ei = (const int*)d_in[1];  // [2,E]: src row then dst row
    const float* W1 = (const float*)d_in[2];
    const float* b1 = (const float*)d_in[3];
    const float* W2 = (const float*)d_in[4];
    const float* b2 = (const float*)d_in[5];
    float* out = (float*)d_out;

    const int* src = ei;
    const int* dst = ei + N_EDGES;

    // workspace layout (~46 MB)
    float* dinv = (float*)d_ws;                       // N
    int* rowptr = (int*)(dinv + N_NODES);             // N+1
    int* bucketfill = rowptr + N_NODES + 1;           // NBUCK
    int* bucketbase = bucketfill + NBUCK;             // NBUCK
    int* colsrc = bucketbase + NBUCK;                 // E
    unsigned short* h1n = (unsigned short*)(colsrc + N_EDGES);  // N*64 bf16 (12.8MB)
    float* h1p = (float*)(h1n + (size_t)N_NODES * DIN);         // N*64 f32 (25.6MB)
    unsigned int* staging = (unsigned int*)h1p;  // alias: staging dead before gather64 writes h1p
    unsigned short* h2n = h1n;                   // alias: h1n dead after gather64

    // CSR build (binning) + norms
    zero_bf_kernel<<<1, 256, 0, stream>>>(bucketfill);
    binpass1_kernel<<<NB1, 256, 0, stream>>>(src, dst, bucketfill, staging);
    scan_buckets_kernel<<<1, 256, 0, stream>>>(bucketfill, bucketbase, rowptr);
    binpass2_kernel<<<NBUCK, 256, 0, stream>>>(staging, bucketfill, bucketbase, rowptr, dinv, colsrc);

    // layer 1
    gemm_k64_n64_kernel<<<N_NODES / 4, 256, 0, stream>>>(x, W1, dinv, h1n);
    gather64_kernel<<<(N_NODES * 64 + 255) / 256, 256, 0, stream>>>(h1n, rowptr, colsrc, dinv, b1, h1p);

    // layer 2
    gemm_k64_n32_kernel<<<N_NODES / 8, 256, 0, stream>>>(h1p, W2, dinv, h2n);
    gather32_kernel<<<(N_NODES * 64 + 255) / 256, 256, 0, stream>>>(h2n, rowptr, colsrc, dinv, b2, out);
}

// Round 9
// 219.442 us; speedup vs baseline: 1.4716x; 1.0247x over previous
//
#include <hip/hip_runtime.h>

#define N_NODES 100000
#define N_EDGES 1600000
#define DIN 64
#define DOUT 32
#define NEG_SLOPE 0.01f
#define NBUCK 196          // buckets of 512 nodes (dst >> 9)
#define CAP 12288          // staging capacity per bucket (mean 8163, ~36 sigma)
#define CH 4096            // edges per binpass1 block
#define NB1 ((N_EDGES + CH - 1) / CH)  // 391

__device__ inline unsigned short f2bf(float f) {  // RNE
    unsigned int u = __float_as_uint(f);
    unsigned int r = (u + 0x7fffu + ((u >> 16) & 1u)) >> 16;
    return (unsigned short)r;
}
__device__ inline float bflo(unsigned int p) { return __uint_as_float(p << 16); }
__device__ inline float bfhi(unsigned int p) { return __uint_as_float(p & 0xffff0000u); }
#define NTL(p) __builtin_nontemporal_load(p)

__device__ inline void addpack4(float* a, uint4 r) {
    a[0] += bflo(r.x); a[1] += bfhi(r.x);
    a[2] += bflo(r.y); a[3] += bfhi(r.y);
    a[4] += bflo(r.z); a[5] += bfhi(r.z);
    a[6] += bflo(r.w); a[7] += bfhi(r.w);
}
__device__ inline void addpack2(float* a, uint2 r) {
    a[0] += bflo(r.x); a[1] += bfhi(r.x);
    a[2] += bflo(r.y); a[3] += bfhi(r.y);
}

// ---------------- binning CSR build ----------------
__global__ void zero_bf_kernel(int* __restrict__ bucketfill) {
    if (threadIdx.x < NBUCK) bucketfill[threadIdx.x] = 0;
}

__global__ __launch_bounds__(256) void binpass1_kernel(const int* __restrict__ src,
                                                       const int* __restrict__ dst,
                                                       int* __restrict__ bucketfill,
                                                       unsigned int* __restrict__ staging) {
    __shared__ int hist[NBUCK];
    __shared__ int cur[NBUCK];
    int tid = threadIdx.x;
    for (int t = tid; t < NBUCK; t += 256) hist[t] = 0;
    __syncthreads();

    int e0 = blockIdx.x * CH + tid;
    int bk[16];
    unsigned int pay[16];
#pragma unroll
    for (int i = 0; i < 16; ++i) {
        int e = e0 + i * 256;
        if (e < N_EDGES) {
            int d = NTL(&dst[e]);
            int s = NTL(&src[e]);
            bk[i] = d >> 9;
            pay[i] = (unsigned int)s | ((unsigned int)(d & 511) << 17);
            atomicAdd(&hist[bk[i]], 1);
        } else {
            bk[i] = -1;
        }
    }
    __syncthreads();
    for (int t = tid; t < NBUCK; t += 256) {
        int h = hist[t];
        cur[t] = h ? atomicAdd(&bucketfill[t], h) : 0;
    }
    __syncthreads();
#pragma unroll
    for (int i = 0; i < 16; ++i) {
        if (bk[i] >= 0) {
            int idx = atomicAdd(&cur[bk[i]], 1);
            if (idx < CAP) staging[(size_t)bk[i] * CAP + idx] = pay[i];
        }
    }
}

__global__ __launch_bounds__(256) void scan_buckets_kernel(const int* __restrict__ bucketfill,
                                                           int* __restrict__ bucketbase,
                                                           int* __restrict__ rowptr) {
    __shared__ int sh[256];
    int t = threadIdx.x;
    int v = (t < NBUCK) ? bucketfill[t] : 0;
    sh[t] = v;
    __syncthreads();
    for (int off = 1; off < 256; off <<= 1) {
        int a = sh[t];
        int add = (t >= off) ? sh[t - off] : 0;
        __syncthreads();
        sh[t] = a + add;
        __syncthreads();
    }
    if (t < NBUCK) bucketbase[t] = sh[t] - v;
    if (t == 0) rowptr[N_NODES] = N_EDGES;
}

__global__ __launch_bounds__(256) void binpass2_kernel(const unsigned int* __restrict__ staging,
                                                       const int* __restrict__ bucketfill,
                                                       const int* __restrict__ bucketbase,
                                                       int* __restrict__ rowptr,
                                                       float* __restrict__ dinv,
                                                       int* __restrict__ colsrc) {
    __shared__ int hist[512];
    __shared__ int posl[512];
    __shared__ int psum[256];
    int b = blockIdx.x;
    int tid = threadIdx.x;
    int base_node = b << 9;
    int nn = min(512, N_NODES - base_node);
    int len = min(bucketfill[b], CAP);
    int bbase = bucketbase[b];
    const unsigned int* stg = staging + (size_t)b * CAP;

    hist[tid] = 0;
    hist[tid + 256] = 0;
    __syncthreads();
    for (int i = tid; i < len; i += 256) atomicAdd(&hist[NTL(&stg[i]) >> 17], 1);
    __syncthreads();

    int a = hist[2 * tid], c = hist[2 * tid + 1];
    psum[tid] = a + c;
    __syncthreads();
    for (int off = 1; off < 256; off <<= 1) {
        int v = psum[tid];
        int add = (tid >= off) ? psum[tid - off] : 0;
        __syncthreads();
        psum[tid] = v + add;
        __syncthreads();
    }
    int pex = tid ? psum[tid - 1] : 0;
    {
        int j0 = 2 * tid, j1 = 2 * tid + 1;
        int e0 = bbase + pex;
        int e1 = e0 + a;
        posl[j0] = e0;
        posl[j1] = e1;
        if (j0 < nn) {
            rowptr[base_node + j0] = e0;
            dinv[base_node + j0] = rsqrtf((float)(a + 1));
        }
        if (j1 < nn) {
            rowptr[base_node + j1] = e1;
            dinv[base_node + j1] = rsqrtf((float)(c + 1));
        }
    }
    __syncthreads();
    for (int i = tid; i < len; i += 256) {
        unsigned int pay = NTL(&stg[i]);
        int dlow = (int)(pay >> 17);
        int idx = atomicAdd(&posl[dlow], 1);
        colsrc[idx] = (int)(pay & 0x1FFFFu);
    }
}

// ---------------- GEMM: Hn = (X @ W) * dinv[row], bf16 out ----------------
__global__ void gemm_k64_n64_kernel(const float* __restrict__ X, const float* __restrict__ W,
                                    const float* __restrict__ dinv,
                                    unsigned short* __restrict__ Hn) {
    __shared__ float Ws[64 * 64];
    __shared__ float Xs[4][64];
    int tid = threadIdx.x;
    {
        const float4* Wv = (const float4*)W;
        float4* Wsv = (float4*)Ws;
#pragma unroll
        for (int i = 0; i < 4; ++i) Wsv[tid + 256 * i] = Wv[tid + 256 * i];
    }
    int row0 = blockIdx.x * 4;
    int r = tid >> 6;
    int col = tid & 63;
    Xs[r][col] = X[(row0 + r) * 64 + col];
    __syncthreads();

    float sum = 0.f;
#pragma unroll
    for (int k = 0; k < 64; ++k) sum += Xs[r][k] * Ws[k * 64 + col];
    Hn[(row0 + r) * 64 + col] = f2bf(sum * dinv[row0 + r]);
}

__global__ void gemm_k64_n32_kernel(const float* __restrict__ X, const float* __restrict__ W,
                                    const float* __restrict__ dinv,
                                    unsigned short* __restrict__ Hn) {
    __shared__ float Ws[64 * 32];
    __shared__ float Xs[8][64];
    int tid = threadIdx.x;
    {
        const float4* Wv = (const float4*)W;
        float4* Wsv = (float4*)Ws;
#pragma unroll
        for (int i = 0; i < 2; ++i) Wsv[tid + 256 * i] = Wv[tid + 256 * i];
    }
    int row0 = blockIdx.x * 8;
    {
        int idx = tid;
#pragma unroll
        for (int i = 0; i < 2; ++i, idx += 256) Xs[idx >> 6][idx & 63] = X[row0 * 64 + idx];
    }
    __syncthreads();

    int r = tid >> 5;
    int col = tid & 31;
    float sum = 0.f;
#pragma unroll
    for (int k = 0; k < 64; ++k) sum += Xs[r][k] * Ws[k * 32 + col];
    Hn[(row0 + r) * 32 + col] = f2bf(sum * dinv[row0 + r]);
}

// ---------------- gather aggregation (bf16 rows, norm pre-folded) ----------------
// wave = 8 groups x 8 lanes; group g owns 1/8 of the edge list; lane loads uint4
// (16B = 8 dims) -> one load instruction covers a whole 128B row for 8 edges at once.
__global__ void gather64_kernel(const unsigned short* __restrict__ Hn,
                                const int* __restrict__ rowptr, const int* __restrict__ colsrc,
                                const float* __restrict__ dinv, const float* __restrict__ bias,
                                float* __restrict__ out) {
    int wid = (blockIdx.x * blockDim.x + threadIdx.x) >> 6;
    int lane = threadIdx.x & 63;
    if (wid >= N_NODES) return;
    int v = wid;
    int g = lane >> 3;
    int sl = lane & 7;
    int gb = g << 3;
    int beg = rowptr[v], end = rowptr[v + 1];
    int len = end - beg;
    int q = len >> 3, r = len & 7;
    int l0 = beg + g * q + min(g, r);
    int l1 = l0 + q + (g < r ? 1 : 0);

    float acc[8], ac2[8];
#pragma unroll
    for (int i = 0; i < 8; ++i) { acc[i] = 0.f; ac2[i] = 0.f; }
    if (g == 0) {  // self row
        uint4 rw = ((const uint4*)(Hn + (size_t)v * 64))[sl];
        addpack4(acc, rw);
    }
    for (int j0 = l0; j0 < l1; j0 += 8) {
        int myj = j0 + sl;
        int s = (myj < l1) ? NTL(&colsrc[myj]) : 0;
        int cnt = min(8, l1 - j0);
        int t = 0;
        for (; t + 2 <= cnt; t += 2) {
            int s0 = __shfl(s, gb + t);
            int s1 = __shfl(s, gb + t + 1);
            uint4 r0 = ((const uint4*)(Hn + (size_t)s0 * 64))[sl];
            uint4 r1 = ((const uint4*)(Hn + (size_t)s1 * 64))[sl];
            addpack4(acc, r0);
            addpack4(ac2, r1);
        }
        if (t < cnt) {
            int s0 = __shfl(s, gb + t);
            uint4 r0 = ((const uint4*)(Hn + (size_t)s0 * 64))[sl];
            addpack4(acc, r0);
        }
    }
#pragma unroll
    for (int i = 0; i < 8; ++i) {
        acc[i] += ac2[i];
        acc[i] += __shfl_xor(acc[i], 8);
        acc[i] += __shfl_xor(acc[i], 16);
        acc[i] += __shfl_xor(acc[i], 32);
    }
    if (g == 0) {
        float dv = dinv[v];
        const float4* bp = (const float4*)(bias + sl * 8);
        float4 b0 = bp[0], b1 = bp[1];
        float o[8];
        o[0] = acc[0] * dv + b0.x; o[1] = acc[1] * dv + b0.y;
        o[2] = acc[2] * dv + b0.z; o[3] = acc[3] * dv + b0.w;
        o[4] = acc[4] * dv + b1.x; o[5] = acc[5] * dv + b1.y;
        o[6] = acc[6] * dv + b1.z; o[7] = acc[7] * dv + b1.w;
#pragma unroll
        for (int i = 0; i < 8; ++i) o[i] = o[i] > 0.f ? o[i] : NEG_SLOPE * o[i];
        float4* op = (float4*)(out + (size_t)v * 64 + sl * 8);
        op[0] = make_float4(o[0], o[1], o[2], o[3]);
        op[1] = make_float4(o[4], o[5], o[6], o[7]);
    }
}

// wave = 8 groups x 8 lanes; lane loads uint2 (8B = 4 dims) -> 64B row per instr.
__global__ void gather32_kernel(const unsigned short* __restrict__ Hn,
                                const int* __restrict__ rowptr, const int* __restrict__ colsrc,
                                const float* __restrict__ dinv, const float* __restrict__ bias,
                                float* __restrict__ out) {
    int wid = (blockIdx.x * blockDim.x + threadIdx.x) >> 6;
    int lane = threadIdx.x & 63;
    if (wid >= N_NODES) return;
    int v = wid;
    int g = lane >> 3;
    int sl = lane & 7;
    int gb = g << 3;
    int beg = rowptr[v], end = rowptr[v + 1];
    int len = end - beg;
    int q = len >> 3, r = len & 7;
    int l0 = beg + g * q + min(g, r);
    int l1 = l0 + q + (g < r ? 1 : 0);

    float acc[4], ac2[4];
#pragma unroll
    for (int i = 0; i < 4; ++i) { acc[i] = 0.f; ac2[i] = 0.f; }
    if (g == 0) {  // self row
        uint2 rw = ((const uint2*)(Hn + (size_t)v * 32))[sl];
        addpack2(acc, rw);
    }
    for (int j0 = l0; j0 < l1; j0 += 8) {
        int myj = j0 + sl;
        int s = (myj < l1) ? NTL(&colsrc[myj]) : 0;
        int cnt = min(8, l1 - j0);
        int t = 0;
        for (; t + 2 <= cnt; t += 2) {
            int s0 = __shfl(s, gb + t);
            int s1 = __shfl(s, gb + t + 1);
            uint2 r0 = ((const uint2*)(Hn + (size_t)s0 * 32))[sl];
            uint2 r1 = ((const uint2*)(Hn + (size_t)s1 * 32))[sl];
            addpack2(acc, r0);
            addpack2(ac2, r1);
        }
        if (t < cnt) {
            int s0 = __shfl(s, gb + t);
            uint2 r0 = ((const uint2*)(Hn + (size_t)s0 * 32))[sl];
            addpack2(acc, r0);
        }
    }
#pragma unroll
    for (int i = 0; i < 4; ++i) {
        acc[i] += ac2[i];
        acc[i] += __shfl_xor(acc[i], 8);
        acc[i] += __shfl_xor(acc[i], 16);
        acc[i] += __shfl_xor(acc[i], 32);
    }
    if (g == 0) {
        float dv = dinv[v];
        float4 bb = *(const float4*)(bias + sl * 4);
        float o0 = acc[0] * dv + bb.x;
        float o1 = acc[1] * dv + bb.y;
        float o2 = acc[2] * dv + bb.z;
        float o3 = acc[3] * dv + bb.w;
        *(float4*)(out + (size_t)v * 32 + sl * 4) = make_float4(o0, o1, o2, o3);
    }
}

extern "C" void kernel_launch(void* const* d_in, const int* in_sizes, int n_in,
                              void* d_out, int out_size, void* d_ws, size_t ws_size,
                              hipStream_t stream) {
    const float* x = (const float*)d_in[0];
    const int* ei = (const int*)d_in[1];  // [2,E]: src row then dst row
    const float* W1 = (const float*)d_in[2];
    const float* b1 = (const float*)d_in[3];
    const float* W2 = (const float*)d_in[4];
    const float* b2 = (const float*)d_in[5];
    float* out = (float*)d_out;

    const int* src = ei;
    const int* dst = ei + N_EDGES;

    // workspace layout (~46 MB)
    float* dinv = (float*)d_ws;                       // N
    int* rowptr = (int*)(dinv + N_NODES);             // N+1
    int* bucketfill = rowptr + N_NODES + 1;           // NBUCK
    int* bucketbase = bucketfill + NBUCK;             // NBUCK
    int* colsrc = bucketbase + NBUCK;                 // E
    unsigned short* h1n = (unsigned short*)(colsrc + N_EDGES);  // N*64 bf16 (12.8MB)
    float* h1p = (float*)(h1n + (size_t)N_NODES * DIN);         // N*64 f32 (25.6MB)
    unsigned int* staging = (unsigned int*)h1p;  // alias: staging dead before gather64 writes h1p
    unsigned short* h2n = h1n;                   // alias: h1n dead after gather64

    // CSR build (binning) + norms
    zero_bf_kernel<<<1, 256, 0, stream>>>(bucketfill);
    binpass1_kernel<<<NB1, 256, 0, stream>>>(src, dst, bucketfill, staging);
    scan_buckets_kernel<<<1, 256, 0, stream>>>(bucketfill, bucketbase, rowptr);
    binpass2_kernel<<<NBUCK, 256, 0, stream>>>(staging, bucketfill, bucketbase, rowptr, dinv, colsrc);

    // layer 1
    gemm_k64_n64_kernel<<<N_NODES / 4, 256, 0, stream>>>(x, W1, dinv, h1n);
    gather64_kernel<<<(N_NODES * 64 + 255) / 256, 256, 0, stream>>>(h1n, rowptr, colsrc, dinv, b1, h1p);

    // layer 2
    gemm_k64_n32_kernel<<<N_NODES / 8, 256, 0, stream>>>(h1p, W2, dinv, h2n);
    gather32_kernel<<<(N_NODES * 64 + 255) / 256, 256, 0, stream>>>(h2n, rowptr, colsrc, dinv, b2, out);
}

// Round 11
// 212.028 us; speedup vs baseline: 1.5230x; 1.0350x over previous
//
#include <hip/hip_runtime.h>

#define N_NODES 100000
#define N_EDGES 1600000
#define DIN 64
#define DOUT 32
#define NEG_SLOPE 0.01f
#define NBUCK 196          // buckets of 512 nodes (dst >> 9)
#define CAP 12288          // staging capacity per bucket (mean 8163, ~36 sigma)
#define CH 4096            // edges per binpass1 block
#define NB1 ((N_EDGES + CH - 1) / CH)  // 391

__device__ inline unsigned short f2bf(float f) {  // RNE
    unsigned int u = __float_as_uint(f);
    unsigned int r = (u + 0x7fffu + ((u >> 16) & 1u)) >> 16;
    return (unsigned short)r;
}
__device__ inline float bflo(unsigned int p) { return __uint_as_float(p << 16); }
__device__ inline float bfhi(unsigned int p) { return __uint_as_float(p & 0xffff0000u); }
#define NTL(p) __builtin_nontemporal_load(p)

__device__ inline void addpack4(float* a, uint4 r) {
    a[0] += bflo(r.x); a[1] += bfhi(r.x);
    a[2] += bflo(r.y); a[3] += bfhi(r.y);
    a[4] += bflo(r.z); a[5] += bfhi(r.z);
    a[6] += bflo(r.w); a[7] += bfhi(r.w);
}
__device__ inline void addpack2(float* a, uint2 r) {
    a[0] += bflo(r.x); a[1] += bfhi(r.x);
    a[2] += bflo(r.y); a[3] += bfhi(r.y);
}

// ---------------- binning CSR build ----------------
__global__ void zero_bf_kernel(int* __restrict__ bucketfill) {
    if (threadIdx.x < NBUCK) bucketfill[threadIdx.x] = 0;
}

__global__ __launch_bounds__(256) void binpass1_kernel(const int* __restrict__ src,
                                                       const int* __restrict__ dst,
                                                       int* __restrict__ bucketfill,
                                                       unsigned int* __restrict__ staging) {
    __shared__ int hist[NBUCK];
    __shared__ int cur[NBUCK];
    int tid = threadIdx.x;
    for (int t = tid; t < NBUCK; t += 256) hist[t] = 0;
    __syncthreads();

    int e0 = blockIdx.x * CH + tid;
    int bk[16];
    unsigned int pay[16];
#pragma unroll
    for (int i = 0; i < 16; ++i) {
        int e = e0 + i * 256;
        if (e < N_EDGES) {
            int d = NTL(&dst[e]);
            int s = NTL(&src[e]);
            bk[i] = d >> 9;
            pay[i] = (unsigned int)s | ((unsigned int)(d & 511) << 17);
            atomicAdd(&hist[bk[i]], 1);
        } else {
            bk[i] = -1;
        }
    }
    __syncthreads();
    for (int t = tid; t < NBUCK; t += 256) {
        int h = hist[t];
        cur[t] = h ? atomicAdd(&bucketfill[t], h) : 0;
    }
    __syncthreads();
#pragma unroll
    for (int i = 0; i < 16; ++i) {
        if (bk[i] >= 0) {
            int idx = atomicAdd(&cur[bk[i]], 1);
            if (idx < CAP) staging[(size_t)bk[i] * CAP + idx] = pay[i];
        }
    }
}

// per-bucket: inline prefix of bucketfill -> node histogram -> scan -> rowptr/dinv
// -> exact CSR placement. colsrc slice dirty only while this block runs.
__global__ __launch_bounds__(256) void binpass2_kernel(const unsigned int* __restrict__ staging,
                                                       const int* __restrict__ bucketfill,
                                                       int* __restrict__ rowptr,
                                                       float* __restrict__ dinv,
                                                       int* __restrict__ colsrc) {
    __shared__ int hist[512];
    __shared__ int posl[512];
    __shared__ int psum[256];
    __shared__ int red[4];
    int b = blockIdx.x;
    int tid = threadIdx.x;
    int base_node = b << 9;
    int nn = min(512, N_NODES - base_node);
    int len = min(bucketfill[b], CAP);
    const unsigned int* stg = staging + (size_t)b * CAP;

    // inline exclusive prefix: bbase = sum_{t<b} bucketfill[t]
    {
        int v = (tid < b) ? bucketfill[tid] : 0;  // b <= 195 < 256
#pragma unroll
        for (int off = 32; off; off >>= 1) v += __shfl_down(v, off);
        if ((tid & 63) == 0) red[tid >> 6] = v;
    }
    hist[tid] = 0;
    hist[tid + 256] = 0;
    __syncthreads();
    int bbase = red[0] + red[1] + red[2] + red[3];

    for (int i = tid; i < len; i += 256) atomicAdd(&hist[NTL(&stg[i]) >> 17], 1);
    __syncthreads();

    int a = hist[2 * tid], c = hist[2 * tid + 1];
    psum[tid] = a + c;
    __syncthreads();
    for (int off = 1; off < 256; off <<= 1) {
        int v = psum[tid];
        int add = (tid >= off) ? psum[tid - off] : 0;
        __syncthreads();
        psum[tid] = v + add;
        __syncthreads();
    }
    int pex = tid ? psum[tid - 1] : 0;
    {
        int j0 = 2 * tid, j1 = 2 * tid + 1;
        int e0 = bbase + pex;
        int e1 = e0 + a;
        posl[j0] = e0;
        posl[j1] = e1;
        if (j0 < nn) {
            rowptr[base_node + j0] = e0;
            dinv[base_node + j0] = rsqrtf((float)(a + 1));
        }
        if (j1 < nn) {
            rowptr[base_node + j1] = e1;
            dinv[base_node + j1] = rsqrtf((float)(c + 1));
        }
    }
    if (b == NBUCK - 1 && tid == 0) rowptr[N_NODES] = N_EDGES;
    __syncthreads();
    for (int i = tid; i < len; i += 256) {
        unsigned int pay = NTL(&stg[i]);
        int dlow = (int)(pay >> 17);
        int idx = atomicAdd(&posl[dlow], 1);
        colsrc[idx] = (int)(pay & 0x1FFFFu);
    }
}

// ---------------- GEMM: Hn = (X @ W1) * dinv[row], bf16 out ----------------
__global__ void gemm_k64_n64_kernel(const float* __restrict__ X, const float* __restrict__ W,
                                    const float* __restrict__ dinv,
                                    unsigned short* __restrict__ Hn) {
    __shared__ float Ws[64 * 64];
    __shared__ float Xs[4][64];
    int tid = threadIdx.x;
    {
        const float4* Wv = (const float4*)W;
        float4* Wsv = (float4*)Ws;
#pragma unroll
        for (int i = 0; i < 4; ++i) Wsv[tid + 256 * i] = Wv[tid + 256 * i];
    }
    int row0 = blockIdx.x * 4;
    int r = tid >> 6;
    int col = tid & 63;
    Xs[r][col] = X[(row0 + r) * 64 + col];
    __syncthreads();

    float sum = 0.f;
#pragma unroll
    for (int k = 0; k < 64; ++k) sum += Xs[r][k] * Ws[k * 64 + col];
    Hn[(row0 + r) * 64 + col] = f2bf(sum * dinv[row0 + r]);
}

// ---------------- fused gather64 + bias/leaky + (row @ W2) * dinv ----------------
// wave = 8 groups x 8 lanes; group g owns 1/8 of the edge list; lane loads uint4.
// After cross-group reduction every lane holds the full 64-dim row; the W2 matmul
// is done in-wave (4 outputs per group from XOR-swizzled LDS W2), h2n written bf16.
// NOTE: h2n MUST NOT alias Hn — neighbor rows are read concurrently with h2n writes.
__global__ __launch_bounds__(256) void gather64_fused_kernel(
    const unsigned short* __restrict__ Hn, const int* __restrict__ rowptr,
    const int* __restrict__ colsrc, const float* __restrict__ dinv,
    const float* __restrict__ bias, const float* __restrict__ W2,
    unsigned short* __restrict__ h2n) {
    __shared__ float W2s[64 * 32];
    {
        // swizzled store: W2s[k*32 + ((jb ^ (k>>3))&7)*4 + (j&3)], jb=j>>2
        int tid = threadIdx.x;
#pragma unroll
        for (int i = 0; i < 8; ++i) {
            int idx = tid + 256 * i;  // k*32 + j
            int k = idx >> 5, j = idx & 31;
            W2s[(k << 5) + (((j >> 2) ^ (k >> 3)) & 7) * 4 + (j & 3)] = W2[idx];
        }
    }
    __syncthreads();

    int wid = (blockIdx.x * blockDim.x + threadIdx.x) >> 6;
    int lane = threadIdx.x & 63;
    if (wid >= N_NODES) return;
    int v = wid;
    int g = lane >> 3;
    int sl = lane & 7;
    int gb = g << 3;
    int beg = rowptr[v], end = rowptr[v + 1];
    int len = end - beg;
    int q = len >> 3, r = len & 7;
    int l0 = beg + g * q + min(g, r);
    int l1 = l0 + q + (g < r ? 1 : 0);

    float acc[8], ac2[8];
#pragma unroll
    for (int i = 0; i < 8; ++i) { acc[i] = 0.f; ac2[i] = 0.f; }
    if (g == 0) {  // self row
        uint4 rw = ((const uint4*)(Hn + (size_t)v * 64))[sl];
        addpack4(acc, rw);
    }
    for (int j0 = l0; j0 < l1; j0 += 8) {
        int myj = j0 + sl;
        int s = (myj < l1) ? NTL(&colsrc[myj]) : 0;
        int cnt = min(8, l1 - j0);
        int t = 0;
        for (; t + 2 <= cnt; t += 2) {
            int s0 = __shfl(s, gb + t);
            int s1 = __shfl(s, gb + t + 1);
            uint4 r0 = ((const uint4*)(Hn + (size_t)s0 * 64))[sl];
            uint4 r1 = ((const uint4*)(Hn + (size_t)s1 * 64))[sl];
            addpack4(acc, r0);
            addpack4(ac2, r1);
        }
        if (t < cnt) {
            int s0 = __shfl(s, gb + t);
            uint4 r0 = ((const uint4*)(Hn + (size_t)s0 * 64))[sl];
            addpack4(acc, r0);
        }
    }
#pragma unroll
    for (int i = 0; i < 8; ++i) {
        acc[i] += ac2[i];
        acc[i] += __shfl_xor(acc[i], 8);
        acc[i] += __shfl_xor(acc[i], 16);
        acc[i] += __shfl_xor(acc[i], 32);
    }
    // every lane now holds full row dims [sl*8, sl*8+8)
    float dv = dinv[v];
    float4 b0 = ((const float4*)(bias + sl * 8))[0];
    float4 b1v = ((const float4*)(bias + sl * 8))[1];
    float row[8];
    row[0] = acc[0] * dv + b0.x;  row[1] = acc[1] * dv + b0.y;
    row[2] = acc[2] * dv + b0.z;  row[3] = acc[3] * dv + b0.w;
    row[4] = acc[4] * dv + b1v.x; row[5] = acc[5] * dv + b1v.y;
    row[6] = acc[6] * dv + b1v.z; row[7] = acc[7] * dv + b1v.w;
#pragma unroll
    for (int i = 0; i < 8; ++i) row[i] = row[i] > 0.f ? row[i] : NEG_SLOPE * row[i];

    // h2[4g+m] partials over k in [sl*8, sl*8+8)
    float p0 = 0.f, p1 = 0.f, p2 = 0.f, p3 = 0.f;
#pragma unroll
    for (int i = 0; i < 8; ++i) {
        int k = sl * 8 + i;
        const float4 wv = *(const float4*)&W2s[(k << 5) + ((g ^ sl) & 7) * 4];
        p0 += row[i] * wv.x;
        p1 += row[i] * wv.y;
        p2 += row[i] * wv.z;
        p3 += row[i] * wv.w;
    }
#pragma unroll
    for (int off = 1; off < 8; off <<= 1) {
        p0 += __shfl_xor(p0, off);
        p1 += __shfl_xor(p1, off);
        p2 += __shfl_xor(p2, off);
        p3 += __shfl_xor(p3, off);
    }
    if (sl == 0) {
        unsigned int lo = (unsigned int)f2bf(p0 * dv) | ((unsigned int)f2bf(p1 * dv) << 16);
        unsigned int hi = (unsigned int)f2bf(p2 * dv) | ((unsigned int)f2bf(p3 * dv) << 16);
        *(uint2*)(h2n + (size_t)v * 32 + (g << 2)) = make_uint2(lo, hi);
    }
}

// wave = 8 groups x 8 lanes; lane loads uint2 (8B = 4 dims); bias fused; final out.
__global__ void gather32_kernel(const unsigned short* __restrict__ Hn,
                                const int* __restrict__ rowptr, const int* __restrict__ colsrc,
                                const float* __restrict__ dinv, const float* __restrict__ bias,
                                float* __restrict__ out) {
    int wid = (blockIdx.x * blockDim.x + threadIdx.x) >> 6;
    int lane = threadIdx.x & 63;
    if (wid >= N_NODES) return;
    int v = wid;
    int g = lane >> 3;
    int sl = lane & 7;
    int gb = g << 3;
    int beg = rowptr[v], end = rowptr[v + 1];
    int len = end - beg;
    int q = len >> 3, r = len & 7;
    int l0 = beg + g * q + min(g, r);
    int l1 = l0 + q + (g < r ? 1 : 0);

    float acc[4], ac2[4];
#pragma unroll
    for (int i = 0; i < 4; ++i) { acc[i] = 0.f; ac2[i] = 0.f; }
    if (g == 0) {  // self row
        uint2 rw = ((const uint2*)(Hn + (size_t)v * 32))[sl];
        addpack2(acc, rw);
    }
    for (int j0 = l0; j0 < l1; j0 += 8) {
        int myj = j0 + sl;
        int s = (myj < l1) ? NTL(&colsrc[myj]) : 0;
        int cnt = min(8, l1 - j0);
        int t = 0;
        for (; t + 2 <= cnt; t += 2) {
            int s0 = __shfl(s, gb + t);
            int s1 = __shfl(s, gb + t + 1);
            uint2 r0 = ((const uint2*)(Hn + (size_t)s0 * 32))[sl];
            uint2 r1 = ((const uint2*)(Hn + (size_t)s1 * 32))[sl];
            addpack2(acc, r0);
            addpack2(ac2, r1);
        }
        if (t < cnt) {
            int s0 = __shfl(s, gb + t);
            uint2 r0 = ((const uint2*)(Hn + (size_t)s0 * 32))[sl];
            addpack2(acc, r0);
        }
    }
#pragma unroll
    for (int i = 0; i < 4; ++i) {
        acc[i] += ac2[i];
        acc[i] += __shfl_xor(acc[i], 8);
        acc[i] += __shfl_xor(acc[i], 16);
        acc[i] += __shfl_xor(acc[i], 32);
    }
    if (g == 0) {
        float dv = dinv[v];
        float4 bb = *(const float4*)(bias + sl * 4);
        float o0 = acc[0] * dv + bb.x;
        float o1 = acc[1] * dv + bb.y;
        float o2 = acc[2] * dv + bb.z;
        float o3 = acc[3] * dv + bb.w;
        *(float4*)(out + (size_t)v * 32 + sl * 4) = make_float4(o0, o1, o2, o3);
    }
}

extern "C" void kernel_launch(void* const* d_in, const int* in_sizes, int n_in,
                              void* d_out, int out_size, void* d_ws, size_t ws_size,
                              hipStream_t stream) {
    const float* x = (const float*)d_in[0];
    const int* ei = (const int*)d_in[1];  // [2,E]: src row then dst row
    const float* W1 = (const float*)d_in[2];
    const float* b1 = (const float*)d_in[3];
    const float* W2 = (const float*)d_in[4];
    const float* b2 = (const float*)d_in[5];
    float* out = (float*)d_out;

    const int* src = ei;
    const int* dst = ei + N_EDGES;

    // workspace layout (~36 MB)
    float* dinv = (float*)d_ws;                       // N
    int* rowptr = (int*)(dinv + N_NODES);             // N+1
    int* bucketfill = rowptr + N_NODES + 1;           // NBUCK
    int* colsrc = bucketfill + NBUCK;                 // E
    unsigned short* h1n = (unsigned short*)(colsrc + N_EDGES);             // N*64 bf16 (12.8MB)
    unsigned short* h2n = h1n + (size_t)N_NODES * DIN;                     // N*32 bf16 (6.4MB) - SEPARATE from h1n
    unsigned int* staging = (unsigned int*)(h2n + (size_t)N_NODES * DOUT); // NBUCK*CAP (9.6MB)

    // CSR build (binning) + norms
    zero_bf_kernel<<<1, 256, 0, stream>>>(bucketfill);
    binpass1_kernel<<<NB1, 256, 0, stream>>>(src, dst, bucketfill, staging);
    binpass2_kernel<<<NBUCK, 256, 0, stream>>>(staging, bucketfill, rowptr, dinv, colsrc);

    // layer 1 GEMM
    gemm_k64_n64_kernel<<<N_NODES / 4, 256, 0, stream>>>(x, W1, dinv, h1n);

    // fused: aggregate layer 1 + bias/leaky + W2 matmul + dinv pre-fold -> h2n
    gather64_fused_kernel<<<(N_NODES * 64 + 255) / 256, 256, 0, stream>>>(
        h1n, rowptr, colsrc, dinv, b1, W2, h2n);

    // layer 2 aggregation -> final output
    gather32_kernel<<<(N_NODES * 64 + 255) / 256, 256, 0, stream>>>(h2n, rowptr, colsrc, dinv, b2, out);
}